// Round 9
// baseline (817.687 us; speedup 1.0000x reference)
//
#include <hip/hip_runtime.h>

typedef unsigned short u16;
typedef short short8 __attribute__((ext_vector_type(8)));
typedef float f32x4 __attribute__((ext_vector_type(4)));

#define MM 18464   // B*N rows
#define NTOK 577

__device__ __forceinline__ u16 f2bf(float f) {
    unsigned u = __builtin_bit_cast(unsigned, f);
    u += 0x7fffu + ((u >> 16) & 1u);
    return (u16)(u >> 16);
}

__device__ __forceinline__ void gload16(const void* g, void* lds) {
    __builtin_amdgcn_global_load_lds(
        (const __attribute__((address_space(1))) unsigned*)g,
        (__attribute__((address_space(3))) unsigned*)lds,
        16, 0, 0);
}

// bijective XCD-chunked remap (m204): consecutive remapped ids share an XCD
__device__ __forceinline__ int xcd_map(int flat, int nwg) {
    const int q = nwg >> 3, r = nwg & 7;
    const int xcd = flat & 7, lid = flat >> 3;
    return (xcd < r ? xcd * (q + 1) : r * (q + 1) + (xcd - r) * q) + lid;
}

__device__ __forceinline__ int2 xcd_swz2(int gx, int gy) {
    const int w = xcd_map(blockIdx.x + blockIdx.y * gx, gx * gy);
    int2 o; o.x = w % gx; o.y = w / gx; return o;
}

// ---------------- weight convert + transpose: src[K][N] f32 -> dst[N][K] bf16 ----------------
__global__ __launch_bounds__(256) void convT(const float* __restrict__ src,
                                             u16* __restrict__ dst, int K, int N) {
    __shared__ float tile[32][33];
    const int k0 = blockIdx.x * 32, n0 = blockIdx.y * 32;
    const int tx = threadIdx.x & 31, ty = threadIdx.x >> 5;  // 32 x 8
#pragma unroll
    for (int i = 0; i < 32; i += 8)
        tile[ty + i][tx] = src[(size_t)(k0 + ty + i) * N + n0 + tx];
    __syncthreads();
#pragma unroll
    for (int i = 0; i < 32; i += 8)
        dst[(size_t)(n0 + ty + i) * K + k0 + tx] = f2bf(tile[tx][ty + i]);
}

// ---------------- layernorm: f32 row[768] -> bf16 ----------------
__global__ __launch_bounds__(192) void ln_k(const float* __restrict__ x,
                                            const float* __restrict__ g,
                                            const float* __restrict__ bt,
                                            u16* __restrict__ out) {
    const int row = blockIdx.x, t = threadIdx.x;
    const float4 v = reinterpret_cast<const float4*>(x + (size_t)row * 768)[t];
    float s = v.x + v.y + v.z + v.w;
    float s2 = v.x * v.x + v.y * v.y + v.z * v.z + v.w * v.w;
#pragma unroll
    for (int off = 32; off > 0; off >>= 1) {
        s += __shfl_down(s, off);
        s2 += __shfl_down(s2, off);
    }
    __shared__ float red[6];
    if ((t & 63) == 0) { red[t >> 6] = s; red[3 + (t >> 6)] = s2; }
    __syncthreads();
    const float S = red[0] + red[1] + red[2];
    const float S2 = red[3] + red[4] + red[5];
    const float mu = S * (1.f / 768.f);
    const float var = S2 * (1.f / 768.f) - mu * mu;
    const float rs = rsqrtf(var + 1e-5f);
    const float4 gg = reinterpret_cast<const float4*>(g)[t];
    const float4 bb = reinterpret_cast<const float4*>(bt)[t];
    ushort4 r;
    r.x = f2bf((v.x - mu) * rs * gg.x + bb.x);
    r.y = f2bf((v.y - mu) * rs * gg.y + bb.y);
    r.z = f2bf((v.z - mu) * rs * gg.z + bb.z);
    r.w = f2bf((v.w - mu) * rs * gg.w + bb.w);
    reinterpret_cast<ushort4*>(out + (size_t)row * 768)[t] = r;
}

// ---------------- GEMM 256x256, BK=64, 8 waves, 2-barrier/tile counted-vmcnt pipeline ------
// C[M][N] = A[M][K](bf16) * BT[N][K](bf16)^T + bias, epilogue per MODE:
// MODE 0: out bf16 = acc + bias                      (qkv)
// MODE 1: out f32  = acc + bias + resid              (proj -> x1)
// MODE 2: out bf16 = gelu(acc + bias)                (fc1)
// MODE 3: out f32  = acc + bias + resid              (fc2 -> d_out)
// LDS planes (u16 offsets): buf*32768 + mat(A=0,B=16384) + kh*8192; each plane
// [256 rows][4 chunks x 16B], chunk ^= (r>>1)&3 (2-way bank alias = free).
// Sync: only {vmcnt(4); s_barrier; sched_barrier} at mid-tile and tile-end.
// Reads of tile tt touch buf only; stages touch buf^1 only -> no other barriers needed.
// MFMA operands SWAPPED (bf,af): lane holds row m=..+l15, cols n=..+lg*4+reg.
template <int MODE>
__global__ __launch_bounds__(512, 2) void gemm_k(const u16* __restrict__ A,
                                                 const u16* __restrict__ BT,
                                                 const float* __restrict__ bias,
                                                 const float* __restrict__ resid,
                                                 void* __restrict__ outp,
                                                 int M, int N, int K, int mt) {
    __shared__ u16 smem[65536];   // 128 KiB
    const int t = threadIdx.x;
    const int wid = t >> 6, lane = t & 63;
    const int l15 = lane & 15, lg = lane >> 4;
    const int wr = wid >> 2, wc = wid & 3;          // 2M x 4N waves
    const int w = xcd_map(blockIdx.x, gridDim.x);
    const int m0 = (w % mt) * 256, n0 = (w / mt) * 256;
    const int swz = (l15 >> 1) & 3;

    // per-thread stage source pointers; M-clamp folded into the base ONCE
    const int rs = t >> 2;
    const int scol = ((t & 3) ^ ((rs >> 1) & 3)) << 3;
    const u16* aP0 = A + (size_t)min(m0 + rs, M - 1) * K + scol;
    const u16* aP1 = A + (size_t)min(m0 + rs + 128, M - 1) * K + scol;
    const u16* bP0 = BT + (size_t)(n0 + rs) * K + scol;
    const u16* bP1 = BT + (size_t)(n0 + rs + 128) * K + scol;
    const int d0 = (t & ~63) * 8, d1 = 4096 + (t & ~63) * 8;   // wave-uniform LDS dests

    // ds_read element offsets within a kh-plane
    const int aRd = (wr * 128 + l15) * 32 + ((lg ^ swz) << 3);
    const int bRd = (wc * 64 + l15) * 32 + ((lg ^ swz) << 3);

    f32x4 acc[8][4] = {};
    const int NT = K >> 6;

    auto stA = [&](int pb, int kk) {
        gload16(aP0 + kk, smem + pb + d0);
        gload16(aP1 + kk, smem + pb + d1);
    };
    auto stB = [&](int pb, int kk) {
        gload16(bP0 + kk, smem + pb + d0);
        gload16(bP1 + kk, smem + pb + d1);
    };

    auto tile = [&](int pb, int kkn, bool pre, bool last) {
        short8 bfv[4], afv[4];
        // ---- p0: mh0, kh0 ----
#pragma unroll
        for (int nf = 0; nf < 4; ++nf)
            bfv[nf] = *(const short8*)&smem[pb + 16384 + bRd + nf * 512];
#pragma unroll
        for (int mf = 0; mf < 4; ++mf)
            afv[mf] = *(const short8*)&smem[pb + aRd + mf * 512];
        if (pre) stA(pb ^ 32768, kkn);
        __builtin_amdgcn_s_setprio(1);
#pragma unroll
        for (int mf = 0; mf < 4; ++mf)
#pragma unroll
            for (int nf = 0; nf < 4; ++nf)
                acc[mf][nf] = __builtin_amdgcn_mfma_f32_16x16x32_bf16(
                    bfv[nf], afv[mf], acc[mf][nf], 0, 0, 0);
        __builtin_amdgcn_s_setprio(0);
        // ---- p1: mh1, kh0 ----
#pragma unroll
        for (int mf = 0; mf < 4; ++mf)
            afv[mf] = *(const short8*)&smem[pb + aRd + 2048 + mf * 512];
        if (pre) stB((pb ^ 32768) + 16384, kkn);
        __builtin_amdgcn_s_setprio(1);
#pragma unroll
        for (int mf = 0; mf < 4; ++mf)
#pragma unroll
            for (int nf = 0; nf < 4; ++nf)
                acc[4 + mf][nf] = __builtin_amdgcn_mfma_f32_16x16x32_bf16(
                    bfv[nf], afv[mf], acc[4 + mf][nf], 0, 0, 0);
        __builtin_amdgcn_s_setprio(0);
        if (last) asm volatile("s_waitcnt vmcnt(0)" ::: "memory");
        else      asm volatile("s_waitcnt vmcnt(4)" ::: "memory");
        __builtin_amdgcn_s_barrier();
        __builtin_amdgcn_sched_barrier(0);
        // ---- p2: mh0, kh1 ----
#pragma unroll
        for (int nf = 0; nf < 4; ++nf)
            bfv[nf] = *(const short8*)&smem[pb + 16384 + 8192 + bRd + nf * 512];
#pragma unroll
        for (int mf = 0; mf < 4; ++mf)
            afv[mf] = *(const short8*)&smem[pb + 8192 + aRd + mf * 512];
        if (pre) stA((pb ^ 32768) + 8192, kkn + 32);
        __builtin_amdgcn_s_setprio(1);
#pragma unroll
        for (int mf = 0; mf < 4; ++mf)
#pragma unroll
            for (int nf = 0; nf < 4; ++nf)
                acc[mf][nf] = __builtin_amdgcn_mfma_f32_16x16x32_bf16(
                    bfv[nf], afv[mf], acc[mf][nf], 0, 0, 0);
        __builtin_amdgcn_s_setprio(0);
        // ---- p3: mh1, kh1 ----
#pragma unroll
        for (int mf = 0; mf < 4; ++mf)
            afv[mf] = *(const short8*)&smem[pb + 8192 + aRd + 2048 + mf * 512];
        if (pre) stB((pb ^ 32768) + 16384 + 8192, kkn + 32);
        __builtin_amdgcn_s_setprio(1);
#pragma unroll
        for (int mf = 0; mf < 4; ++mf)
#pragma unroll
            for (int nf = 0; nf < 4; ++nf)
                acc[4 + mf][nf] = __builtin_amdgcn_mfma_f32_16x16x32_bf16(
                    bfv[nf], afv[mf], acc[4 + mf][nf], 0, 0, 0);
        __builtin_amdgcn_s_setprio(0);
        if (pre) {
            asm volatile("s_waitcnt vmcnt(4)" ::: "memory");
            __builtin_amdgcn_s_barrier();
            __builtin_amdgcn_sched_barrier(0);
        }
    };

    // prologue: tile 0 fully staged; k0 group must be OLDEST (sched fence between groups)
    stA(0, 0); stB(16384, 0);
    __builtin_amdgcn_sched_barrier(0);
    stA(8192, 32); stB(16384 + 8192, 32);
    asm volatile("s_waitcnt vmcnt(4)" ::: "memory");
    __builtin_amdgcn_s_barrier();
    __builtin_amdgcn_sched_barrier(0);

    int kkn = 64;
    const int half = NT >> 1;
    for (int it = 0; it < half; ++it) {
        tile(0, kkn, true, false);
        kkn += 64;
        const bool pre = (it + 1 < half);
        tile(32768, kkn, pre, !pre);
        kkn += 64;
    }

    // ---------------- epilogue: per-wave LDS bounce -> coalesced stores ----------------
    __syncthreads();
    const int col = n0 + wc * 64 + l15 * 4;
    const float4 bias4 = *(const float4*)&bias[col];
#pragma unroll
    for (int mf = 0; mf < 8; ++mf) {
        float* ws_ = (float*)smem + wid * 2144 + (mf & 1) * 1072;  // dbuf slices (WAR)
        // WAR safety: slice (mf&1) was read at iteration mf-2 by THIS wave only;
        // ensure those ds_reads retired before overwriting (type-punned pointers
        // may defeat the compiler's alias-based waitcnt insertion).
        asm volatile("s_waitcnt lgkmcnt(0)" ::: "memory");
#pragma unroll
        for (int nf = 0; nf < 4; ++nf)
            *(f32x4*)&ws_[l15 * 67 + nf * 16 + lg * 4] = acc[mf][nf];
#pragma unroll
        for (int ps = 0; ps < 4; ++ps) {
            const int rl = ps * 4 + lg;
            float4 v = *(const float4*)&ws_[rl * 67 + l15 * 4];
            v.x += bias4.x; v.y += bias4.y; v.z += bias4.z; v.w += bias4.w;
            if (MODE == 2) {
                v.x = 0.5f * v.x * (1.0f + erff(v.x * 0.70710678118f));
                v.y = 0.5f * v.y * (1.0f + erff(v.y * 0.70710678118f));
                v.z = 0.5f * v.z * (1.0f + erff(v.z * 0.70710678118f));
                v.w = 0.5f * v.w * (1.0f + erff(v.w * 0.70710678118f));
            }
            const int grow = m0 + wr * 128 + mf * 16 + rl;
            if (grow < M) {
                if (MODE == 1 || MODE == 3) {
                    const float4 rr = *(const float4*)&resid[(size_t)grow * N + col];
                    v.x += rr.x; v.y += rr.y; v.z += rr.z; v.w += rr.w;
                }
                if (MODE == 0 || MODE == 2) {
                    ushort4 r4;
                    r4.x = f2bf(v.x); r4.y = f2bf(v.y);
                    r4.z = f2bf(v.z); r4.w = f2bf(v.w);
                    *(ushort4*)&((u16*)outp)[(size_t)grow * N + col] = r4;
                } else {
                    *(float4*)&((float*)outp)[(size_t)grow * N + col] = v;
                }
            }
        }
    }
}

// ---------------- flash attention over qkv[M][2304] bf16, out o[M][768] bf16 ----------------
__global__ __launch_bounds__(256) void attn_k(const u16* __restrict__ qkv,
                                              u16* __restrict__ o) {
    const int2 sw = xcd_swz2(10, 384);
    const int qt = sw.x;             // 0..9
    const int bh = sw.y;             // 0..383
    const int b = bh / 12, h = bh % 12;
    const int t = threadIdx.x, wid = t >> 6, lane = t & 63;
    const int l15 = lane & 15, lg = lane >> 4;
    const size_t base = ((size_t)b * NTOK) * 2304 + (size_t)h * 64;

    __shared__ u16 Ks[64 * 64], VT[64 * 64], Ps[64 * 64];

    int qrow = qt * 64 + wid * 16 + l15;
    qrow = min(qrow, NTOK - 1);
    const u16* Qp = qkv + base + (size_t)qrow * 2304 + lg * 8;
    const short8 qf0 = *(const short8*)(Qp);
    const short8 qf1 = *(const short8*)(Qp + 32);

    f32x4 oacc[4] = {};
    float m_run[4], l_run[4];
#pragma unroll
    for (int j = 0; j < 4; ++j) { m_run[j] = -1e30f; l_run[j] = 0.f; }

    const int srow = t >> 3;               // 0..31 (kv row within half-tile)
    const int cchunk = t & 7;              // 16B chunk within 128B row
    const int ksd = (cchunk ^ (srow & 7)) * 8;   // pre-swizzled K source offset
    u16* ldsK = Ks + wid * 512;
    const int vs0 = ((srow >> 3) ^ cchunk) * 8 + (srow & 7);
    const int vs1 = (((srow >> 3) + 4) ^ cchunk) * 8 + (srow & 7);

    for (int kt = 0; kt < 10; ++kt) {
        const int n0t = kt * 64;
        const int r0 = min(n0t + srow, NTOK - 1);
        const int r1 = min(n0t + srow + 32, NTOK - 1);
        gload16(qkv + base + 768 + (size_t)r0 * 2304 + ksd, ldsK);
        gload16(qkv + base + 768 + (size_t)r1 * 2304 + ksd, ldsK + 2048);
        const short8 v0 = *(const short8*)(qkv + base + 1536 + (size_t)r0 * 2304 + cchunk * 8);
        const short8 v1 = *(const short8*)(qkv + base + 1536 + (size_t)r1 * 2304 + cchunk * 8);
#pragma unroll
        for (int j = 0; j < 8; ++j) {
            VT[(cchunk * 8 + j) * 64 + vs0] = (u16)v0[j];
            VT[(cchunk * 8 + j) * 64 + vs1] = (u16)v1[j];
        }
        __syncthreads();

        // S = Q K^T
        f32x4 s[4];
#pragma unroll
        for (int fc = 0; fc < 4; ++fc) {
            const int krow = fc * 16 + l15;
            const short8 kf0 = *(const short8*)&Ks[krow * 64 + ((lg ^ (krow & 7)) * 8)];
            const short8 kf1 = *(const short8*)&Ks[krow * 64 + (((lg + 4) ^ (krow & 7)) * 8)];
            f32x4 a_ = {};
            a_ = __builtin_amdgcn_mfma_f32_16x16x32_bf16(qf0, kf0, a_, 0, 0, 0);
            a_ = __builtin_amdgcn_mfma_f32_16x16x32_bf16(qf1, kf1, a_, 0, 0, 0);
            s[fc] = a_;
        }
#pragma unroll
        for (int fc = 0; fc < 4; ++fc) {
            const bool valid = (n0t + fc * 16 + l15) < NTOK;
#pragma unroll
            for (int j = 0; j < 4; ++j)
                s[fc][j] = valid ? s[fc][j] * 0.125f : -1e30f;
        }
        float mt_[4];
#pragma unroll
        for (int j = 0; j < 4; ++j)
            mt_[j] = fmaxf(fmaxf(s[0][j], s[1][j]), fmaxf(s[2][j], s[3][j]));
#pragma unroll
        for (int off = 1; off < 16; off <<= 1)
#pragma unroll
            for (int j = 0; j < 4; ++j) mt_[j] = fmaxf(mt_[j], __shfl_xor(mt_[j], off));
        float mn[4], alpha[4];
#pragma unroll
        for (int j = 0; j < 4; ++j) {
            mn[j] = fmaxf(m_run[j], mt_[j]);
            alpha[j] = __expf(m_run[j] - mn[j]);
            m_run[j] = mn[j];
        }
        float lsum[4] = {0.f, 0.f, 0.f, 0.f};
#pragma unroll
        for (int fc = 0; fc < 4; ++fc)
#pragma unroll
            for (int j = 0; j < 4; ++j) {
                const float p = __expf(s[fc][j] - mn[j]);
                s[fc][j] = p;
                lsum[j] += p;
            }
#pragma unroll
        for (int off = 1; off < 16; off <<= 1)
#pragma unroll
            for (int j = 0; j < 4; ++j) lsum[j] += __shfl_xor(lsum[j], off);
#pragma unroll
        for (int j = 0; j < 4; ++j) l_run[j] = l_run[j] * alpha[j] + lsum[j];
#pragma unroll
        for (int fc = 0; fc < 4; ++fc)
#pragma unroll
            for (int j = 0; j < 4; ++j) oacc[fc][j] *= alpha[j];

#pragma unroll
        for (int fc = 0; fc < 4; ++fc)
#pragma unroll
            for (int j = 0; j < 4; ++j) {
                const int q = wid * 16 + lg * 4 + j;
                Ps[q * 64 + (((fc * 2 + (l15 >> 3)) ^ (q & 7)) * 8) + (l15 & 7)] =
                    f2bf(s[fc][j]);
            }
        asm volatile("s_waitcnt lgkmcnt(0)" ::: "memory");

#pragma unroll
        for (int c = 0; c < 2; ++c) {
            const short8 pf = *(const short8*)
                &Ps[(wid * 16 + l15) * 64 + (((c * 4 + lg) ^ (l15 & 7)) * 8)];
#pragma unroll
            for (int fc = 0; fc < 4; ++fc) {
                const short8 vf = *(const short8*)
                    &VT[(fc * 16 + l15) * 64 +
                        (((c * 4 + lg) ^ (fc * 2 + (l15 >> 3))) * 8)];
                oacc[fc] = __builtin_amdgcn_mfma_f32_16x16x32_bf16(pf, vf, oacc[fc], 0, 0, 0);
            }
        }
        __syncthreads();
    }

#pragma unroll
    for (int j = 0; j < 4; ++j) {
        const int row = qt * 64 + wid * 16 + lg * 4 + j;
        if (row < NTOK) {
            const float inv = 1.0f / l_run[j];
#pragma unroll
            for (int fc = 0; fc < 4; ++fc)
                o[((size_t)(b * NTOK + row)) * 768 + h * 64 + fc * 16 + l15] =
                    f2bf(oacc[fc][j] * inv);
        }
    }
}

extern "C" void kernel_launch(void* const* d_in, const int* in_sizes, int n_in,
                              void* d_out, int out_size, void* d_ws, size_t ws_size,
                              hipStream_t stream) {
    const float* x      = (const float*)d_in[0];
    const float* ln1_g  = (const float*)d_in[1];
    const float* ln1_b  = (const float*)d_in[2];
    const float* qkv_w  = (const float*)d_in[3];
    const float* qkv_b  = (const float*)d_in[4];
    const float* proj_w = (const float*)d_in[5];
    const float* proj_b = (const float*)d_in[6];
    const float* ln2_g  = (const float*)d_in[7];
    const float* ln2_b  = (const float*)d_in[8];
    const float* fc1_w  = (const float*)d_in[9];
    const float* fc1_b  = (const float*)d_in[10];
    const float* fc2_w  = (const float*)d_in[11];
    const float* fc2_b  = (const float*)d_in[12];
    float* out = (float*)d_out;

    char* ws = (char*)d_ws;
    size_t off = 0;
    u16* WQ  = (u16*)(ws + off); off += (size_t)2304 * 768 * 2;   // qkv_w^T
    u16* WP  = (u16*)(ws + off); off += (size_t)768 * 768 * 2;    // proj_w^T
    u16* W1  = (u16*)(ws + off); off += (size_t)3072 * 768 * 2;   // fc1_w^T
    u16* W2  = (u16*)(ws + off); off += (size_t)768 * 3072 * 2;   // fc2_w^T
    u16* LN1 = (u16*)(ws + off); off += (size_t)MM * 768 * 2;
    u16* QKV = (u16*)(ws + off); off += (size_t)MM * 2304 * 2;
    u16* OB  = (u16*)(ws + off); off += (size_t)MM * 768 * 2;
    float* X1 = (float*)(ws + off); off += (size_t)MM * 768 * 4;
    u16* LN2 = (u16*)(ws + off); off += (size_t)MM * 768 * 2;
    u16* HID = LN1;  // aliases LN1+QKV (dead by fc1)

    // weights -> bf16 transposed
    convT<<<dim3(24, 72), 256, 0, stream>>>(qkv_w, WQ, 768, 2304);
    convT<<<dim3(24, 24), 256, 0, stream>>>(proj_w, WP, 768, 768);
    convT<<<dim3(24, 96), 256, 0, stream>>>(fc1_w, W1, 768, 3072);
    convT<<<dim3(96, 24), 256, 0, stream>>>(fc2_w, W2, 3072, 768);

    const int mt = (MM + 255) / 256;   // 73 row tiles
    // MSA branch
    ln_k<<<MM, 192, 0, stream>>>(x, ln1_g, ln1_b, LN1);
    gemm_k<0><<<mt * 9, 512, 0, stream>>>(LN1, WQ, qkv_b, nullptr, QKV,
                                          MM, 2304, 768, mt);
    attn_k<<<dim3(10, 384), 256, 0, stream>>>(QKV, OB);
    gemm_k<1><<<mt * 3, 512, 0, stream>>>(OB, WP, proj_b, x, X1,
                                          MM, 768, 768, mt);
    // MLP branch
    ln_k<<<MM, 192, 0, stream>>>(X1, ln2_g, ln2_b, LN2);
    gemm_k<2><<<mt * 12, 512, 0, stream>>>(LN2, W1, fc1_b, nullptr, HID,
                                           MM, 3072, 768, mt);
    gemm_k<3><<<mt * 3, 512, 0, stream>>>(HID, W2, fc2_b, X1, out,
                                          MM, 768, 3072, mt);
}